// Round 6
// baseline (55.194 us; speedup 1.0000x reference)
//
#include <hip/hip_runtime.h>

#define H 64
#define W 64
#define NPIX 4096          // 64*64
#define GHH 240
#define GWW 240
#define CB 512             // total channels in data
#define CX 256             // x channels
#define NT4  16            // taps packed 4-per-uint4

typedef float f32x2 __attribute__((ext_vector_type(2)));   // native vec for nontemporal store

// ---------- helpers: bf16 pack/unpack ----------
static __device__ __forceinline__ unsigned pk_bf16(float a, float b) {
    unsigned ua = __float_as_uint(a);
    ua = (ua + 0x7fffu + ((ua >> 16) & 1u)) >> 16;          // bf16(a) in low 16
    unsigned ub = __float_as_uint(b);
    ub = (ub + 0x7fffu + ((ub >> 16) & 1u)) & 0xffff0000u;  // bf16(b) in high 16
    return ua | ub;
}
static __device__ __forceinline__ float lo_bf16(unsigned u) { return __uint_as_float(u << 16); }
static __device__ __forceinline__ float hi_bf16(unsigned u) { return __uint_as_float(u & 0xffff0000u); }
// weight packed in HIGH 16 bits (float-ready via one AND), idx in low 16
static __device__ __forceinline__ unsigned pk_wi(float w, unsigned idx) {
    unsigned ub = __float_as_uint(w);
    ub = (ub + 0x7fffu + ((ub >> 16) & 1u)) & 0xffff0000u;
    return ub | idx;
}

// ---------- kernel 1: per (b,pixel) 64-tap packed stencil -> ws ----------
// grid: 128 blocks x 256 threads; b = blockIdx&7 so batch-b stencil is written
// from (and L2-resident on) the same XCD that gathers batch b.
__global__ __launch_bounds__(256)
void stencil_kernel(const float* __restrict__ data, uint4* __restrict__ st) {
    const int b   = blockIdx.x & 7;
    const int pix = (blockIdx.x >> 3) * 256 + threadIdx.x;
    const int oy = pix >> 6, ox = pix & 63;

    const float*  xbase = data + (size_t)b * CB * NPIX;
    const float2* gaff  = (const float2*)(xbase + (size_t)256 * NPIX);
    const float2* gtps  = (const float2*)(xbase + (size_t)384 * NPIX);
    uint4* stb = st + (size_t)b * NT4 * NPIX;

    const float fy  = ((float)oy / 63.0f) * 239.0f;
    const float fx  = ((float)ox / 63.0f) * 239.0f;
    const float fy0 = floorf(fy), fx0 = floorf(fx);
    const float wy1 = fy - fy0,  wx1 = fx - fx0;

#pragma unroll
    for (int t = 0; t < 4; ++t) {
        const int tty = t >> 1, ttx = t & 1;
        const float gyf = fy0 + (float)tty;
        const float gxf = fx0 + (float)ttx;
        float wt = (tty ? wy1 : 1.0f - wy1) * (ttx ? wx1 : 1.0f - wx1);
        if (gyf < 0.0f || gyf > 239.0f || gxf < 0.0f || gxf > 239.0f) wt = 0.0f;
        const int gyi = min(max((int)gyf, 0), GHH - 1);
        const int gxi = min(max((int)gxf, 0), GWW - 1);

        const float2 gt = gtps[gyi * GWW + gxi];
        const float sx  = (gt.x + 1.0f) * 0.5f * 239.0f;
        const float sy  = (gt.y + 1.0f) * 0.5f * 239.0f;
        const float sy0 = floorf(sy), sx0 = floorf(sx);
        const float wsy1 = sy - sy0,  wsx1 = sx - sx0;

#pragma unroll
        for (int s = 0; s < 4; ++s) {
            const int ssy = s >> 1, ssx = s & 1;
            const float ayf = sy0 + (float)ssy;
            const float axf = sx0 + (float)ssx;
            float ws = (ssy ? wsy1 : 1.0f - wsy1) * (ssx ? wsx1 : 1.0f - wsx1);
            if (ayf < 0.0f || ayf > 239.0f || axf < 0.0f || axf > 239.0f) ws = 0.0f;
            ws *= wt;
            const int ayi = min(max((int)ayf, 0), GHH - 1);
            const int axi = min(max((int)axf, 0), GWW - 1);

            const float2 ga = gaff[ayi * GWW + axi];
            const float qx  = (ga.x + 1.0f) * 0.5f * 63.0f;
            const float qy  = (ga.y + 1.0f) * 0.5f * 63.0f;
            const float qy0 = floorf(qy), qx0 = floorf(qx);
            const float wqy1 = qy - qy0,  wqx1 = qx - qx0;

            unsigned pk[4];
#pragma unroll
            for (int r = 0; r < 4; ++r) {
                const int rry = r >> 1, rrx = r & 1;
                const float byf = qy0 + (float)rry;
                const float bxf = qx0 + (float)rrx;
                float wr = (rry ? wqy1 : 1.0f - wqy1) * (rrx ? wqx1 : 1.0f - wqx1);
                if (byf < 0.0f || byf > 63.0f || bxf < 0.0f || bxf > 63.0f) wr = 0.0f;
                wr *= ws;
                const int byi = min(max((int)byf, 0), H - 1);
                const int bxi = min(max((int)bxf, 0), W - 1);
                pk[r] = pk_wi(wr, (unsigned)(byi * W + bxi));
            }
            stb[(size_t)(t * 4 + s) * NPIX + pix] = make_uint4(pk[0], pk[1], pk[2], pk[3]);
        }
    }
}

// ---------- kernel 2: gather-FMA over bf16-packed LDS ----------
// grid: 8 b x 32 cg x 2 halves = 512 blocks x 1024 threads; 64 KB LDS each
// -> 2 blocks/CU, 32 waves/CU. Thread owns 2 consecutive pixels.
__global__ __launch_bounds__(1024, 8)
void gather_kernel(const float* __restrict__ data, const uint4* __restrict__ st,
                   float* __restrict__ out) {
    __shared__ uint4 xl[NPIX];   // 64 KB: pixel -> 8 channels packed bf16
    const int tid  = threadIdx.x;
    const int b    = blockIdx.x & 7;        // XCD pinning heuristic
    const int cg   = (blockIdx.x >> 3) & 31;
    const int half = blockIdx.x >> 8;       // 0/1: pixel half
    const int c0   = cg * 8;

    const float* xbase = data + (size_t)b * CB * NPIX;
    const float* xc    = xbase + (size_t)c0 * NPIX;

    // stage full 8-channel image: 8 x float4 coalesced loads, register transpose
    {
        float4 va[8];
#pragma unroll
        for (int c = 0; c < 8; ++c)
            va[c] = ((const float4*)(xc + (size_t)c * NPIX))[tid];
#pragma unroll
        for (int k = 0; k < 4; ++k) {
            uint4 u;
            u.x = pk_bf16(((const float*)&va[0])[k], ((const float*)&va[1])[k]);
            u.y = pk_bf16(((const float*)&va[2])[k], ((const float*)&va[3])[k]);
            u.z = pk_bf16(((const float*)&va[4])[k], ((const float*)&va[5])[k]);
            u.w = pk_bf16(((const float*)&va[6])[k], ((const float*)&va[7])[k]);
            xl[tid * 4 + k] = u;
        }
    }
    __syncthreads();

    const uint4* stb = st + (size_t)b * NT4 * NPIX;
    const int pix0 = half * 2048 + tid * 2;   // even; owns pix0, pix0+1

    float a0[8], a1[8];
#pragma unroll
    for (int c = 0; c < 8; ++c) { a0[c] = 0.f; a1[c] = 0.f; }

#pragma unroll 4
    for (int g = 0; g < NT4; ++g) {
        const uint4 sa = stb[(size_t)g * NPIX + pix0];
        const uint4 sb = stb[(size_t)g * NPIX + pix0 + 1];
#pragma unroll
        for (int r = 0; r < 4; ++r) {
            const unsigned ua = (&sa.x)[r];
            const unsigned ub = (&sb.x)[r];
            const float wa = __uint_as_float(ua & 0xffff0000u);
            const float wb = __uint_as_float(ub & 0xffff0000u);
            const uint4 va = xl[ua & 0xffffu];
            const uint4 vb = xl[ub & 0xffffu];
            a0[0] = fmaf(wa, lo_bf16(va.x), a0[0]); a1[0] = fmaf(wb, lo_bf16(vb.x), a1[0]);
            a0[1] = fmaf(wa, hi_bf16(va.x), a0[1]); a1[1] = fmaf(wb, hi_bf16(vb.x), a1[1]);
            a0[2] = fmaf(wa, lo_bf16(va.y), a0[2]); a1[2] = fmaf(wb, lo_bf16(vb.y), a1[2]);
            a0[3] = fmaf(wa, hi_bf16(va.y), a0[3]); a1[3] = fmaf(wb, hi_bf16(vb.y), a1[3]);
            a0[4] = fmaf(wa, lo_bf16(va.z), a0[4]); a1[4] = fmaf(wb, lo_bf16(vb.z), a1[4]);
            a0[5] = fmaf(wa, hi_bf16(va.z), a0[5]); a1[5] = fmaf(wb, hi_bf16(vb.z), a1[5]);
            a0[6] = fmaf(wa, lo_bf16(va.w), a0[6]); a1[6] = fmaf(wb, lo_bf16(vb.w), a1[6]);
            a0[7] = fmaf(wa, hi_bf16(va.w), a0[7]); a1[7] = fmaf(wb, hi_bf16(vb.w), a1[7]);
        }
    }

    // residual (f32 from global, L2-resident) + paired non-temporal stores
#pragma unroll
    for (int c = 0; c < 8; ++c) {
        const float2 rv = ((const float2*)(xc + (size_t)c * NPIX))[pix0 >> 1];
        f32x2 ov;
        ov.x = rv.x + a0[c];
        ov.y = rv.y + a1[c];
        f32x2* op = (f32x2*)(out + ((size_t)b * CX + c0 + c) * NPIX + pix0);
        __builtin_nontemporal_store(ov, op);
    }
}

// ---------- fallback (round-2 proven kernel) if ws too small ----------
__global__ __launch_bounds__(1024, 4)
void warp_resblock_mono(const float* __restrict__ data, float* __restrict__ out) {
    const int tid = threadIdx.x;
    const int b   = blockIdx.x & 7;
    const int cg  = blockIdx.x >> 3;
    const int c0  = cg * 8;

    const float*  xbase = data + (size_t)b * CB * NPIX;
    const float2* gaff  = (const float2*)(xbase + (size_t)256 * NPIX);
    const float2* gtps  = (const float2*)(xbase + (size_t)384 * NPIX);

    __shared__ float4 xa[NPIX];
    __shared__ float4 xb[NPIX];
    {
        const float4* xs = (const float4*)(xbase + (size_t)c0 * NPIX);
        float4 va[4], vb[4];
#pragma unroll
        for (int cc = 0; cc < 4; ++cc) va[cc] = xs[(size_t)cc * 1024 + tid];
#pragma unroll
        for (int cc = 0; cc < 4; ++cc) vb[cc] = xs[(size_t)(4 + cc) * 1024 + tid];
#pragma unroll
        for (int k = 0; k < 4; ++k) {
            const int pix = tid * 4 + k;
            xa[pix] = make_float4(((const float*)&va[0])[k], ((const float*)&va[1])[k],
                                  ((const float*)&va[2])[k], ((const float*)&va[3])[k]);
            xb[pix] = make_float4(((const float*)&vb[0])[k], ((const float*)&vb[1])[k],
                                  ((const float*)&vb[2])[k], ((const float*)&vb[3])[k]);
        }
    }
    __syncthreads();

    for (int pg = 0; pg < 4; ++pg) {
        const int pix = pg * 1024 + tid;
        const int oy = pix >> 6, ox = pix & 63;
        float a0 = 0.f, a1 = 0.f, a2 = 0.f, a3 = 0.f;
        float a4 = 0.f, a5 = 0.f, a6 = 0.f, a7 = 0.f;

        const float fy  = ((float)oy / 63.0f) * 239.0f;
        const float fx  = ((float)ox / 63.0f) * 239.0f;
        const float fy0 = floorf(fy), fx0 = floorf(fx);
        const float wy1 = fy - fy0,  wx1 = fx - fx0;

#pragma unroll
        for (int t = 0; t < 4; ++t) {
            const int tty = t >> 1, ttx = t & 1;
            const float gyf = fy0 + (float)tty;
            const float gxf = fx0 + (float)ttx;
            float wt = (tty ? wy1 : 1.0f - wy1) * (ttx ? wx1 : 1.0f - wx1);
            if (gyf < 0.0f || gyf > 239.0f || gxf < 0.0f || gxf > 239.0f) wt = 0.0f;
            const int gyi = min(max((int)gyf, 0), GHH - 1);
            const int gxi = min(max((int)gxf, 0), GWW - 1);
            const float2 gt = gtps[gyi * GWW + gxi];
            const float sx  = (gt.x + 1.0f) * 0.5f * 239.0f;
            const float sy  = (gt.y + 1.0f) * 0.5f * 239.0f;
            const float sy0 = floorf(sy), sx0 = floorf(sx);
            const float wsy1 = sy - sy0,  wsx1 = sx - sx0;
#pragma unroll
            for (int s = 0; s < 4; ++s) {
                const int ssy = s >> 1, ssx = s & 1;
                const float ayf = sy0 + (float)ssy;
                const float axf = sx0 + (float)ssx;
                float ws = (ssy ? wsy1 : 1.0f - wsy1) * (ssx ? wsx1 : 1.0f - wsx1);
                if (ayf < 0.0f || ayf > 239.0f || axf < 0.0f || axf > 239.0f) ws = 0.0f;
                ws *= wt;
                const int ayi = min(max((int)ayf, 0), GHH - 1);
                const int axi = min(max((int)axf, 0), GWW - 1);
                const float2 ga = gaff[ayi * GWW + axi];
                const float qx  = (ga.x + 1.0f) * 0.5f * 63.0f;
                const float qy  = (ga.y + 1.0f) * 0.5f * 63.0f;
                const float qy0 = floorf(qy), qx0 = floorf(qx);
                const float wqy1 = qy - qy0,  wqx1 = qx - qx0;
#pragma unroll
                for (int r = 0; r < 4; ++r) {
                    const int rry = r >> 1, rrx = r & 1;
                    const float byf = qy0 + (float)rry;
                    const float bxf = qx0 + (float)rrx;
                    float wr = (rry ? wqy1 : 1.0f - wqy1) * (rrx ? wqx1 : 1.0f - wqx1);
                    if (byf < 0.0f || byf > 63.0f || bxf < 0.0f || bxf > 63.0f) wr = 0.0f;
                    wr *= ws;
                    const int byi = min(max((int)byf, 0), H - 1);
                    const int bxi = min(max((int)bxf, 0), W - 1);
                    const int idx = byi * W + bxi;
                    const float4 pa = xa[idx];
                    const float4 pb = xb[idx];
                    a0 = fmaf(wr, pa.x, a0); a1 = fmaf(wr, pa.y, a1);
                    a2 = fmaf(wr, pa.z, a2); a3 = fmaf(wr, pa.w, a3);
                    a4 = fmaf(wr, pb.x, a4); a5 = fmaf(wr, pb.y, a5);
                    a6 = fmaf(wr, pb.z, a6); a7 = fmaf(wr, pb.w, a7);
                }
            }
        }
        const float4 ra = xa[pix];
        const float4 rb = xb[pix];
        float* o = out + ((size_t)b * CX + c0) * NPIX + pix;
        o[0 * NPIX] = ra.x + a0; o[1 * NPIX] = ra.y + a1;
        o[2 * NPIX] = ra.z + a2; o[3 * NPIX] = ra.w + a3;
        o[4 * NPIX] = rb.x + a4; o[5 * NPIX] = rb.y + a5;
        o[6 * NPIX] = rb.z + a6; o[7 * NPIX] = rb.w + a7;
    }
}

extern "C" void kernel_launch(void* const* d_in, const int* in_sizes, int n_in,
                              void* d_out, int out_size, void* d_ws, size_t ws_size,
                              hipStream_t stream) {
    (void)in_sizes; (void)n_in; (void)out_size;
    const float* data = (const float*)d_in[0];
    float* out = (float*)d_out;
    const size_t ws_needed = (size_t)8 * NT4 * NPIX * sizeof(uint4);  // 8.39 MB

    if (ws_size >= ws_needed) {
        uint4* st = (uint4*)d_ws;
        hipLaunchKernelGGL(stencil_kernel, dim3(128), dim3(256), 0, stream, data, st);
        hipLaunchKernelGGL(gather_kernel, dim3(512), dim3(1024), 0, stream, data, st, out);
    } else {
        hipLaunchKernelGGL(warp_resblock_mono, dim3(256), dim3(1024), 0, stream, data, out);
    }
}

// Round 7
// 52.980 us; speedup vs baseline: 1.0418x; 1.0418x over previous
//
#include <hip/hip_runtime.h>
#include <hip/hip_fp16.h>

#define H 64
#define W 64
#define NPIX 4096          // 64*64
#define GHH 240
#define GWW 240
#define CB 512             // total channels in data
#define CX 256             // x channels
#define NT4  16            // taps packed 4-per-uint4

// ---------- helpers ----------
// weight packed in HIGH 16 bits (float-ready via one AND), idx in low 16
static __device__ __forceinline__ unsigned pk_wi(float w, unsigned idx) {
    unsigned ub = __float_as_uint(w);
    ub = (ub + 0x7fffu + ((ub >> 16) & 1u)) & 0xffff0000u;
    return ub | idx;
}
// pack two f32 -> packed f16 pair (v_cvt_pkrtz_f16_f32, one instruction)
static __device__ __forceinline__ unsigned pk_f16(float a, float b) {
    __half2 h = __floats2half2_rn(a, b);
    return *reinterpret_cast<unsigned*>(&h);
}

// ---------- kernel 1: per (b,pixel) 64-tap packed stencil -> ws ----------
// grid: 128 blocks x 256 threads; b = blockIdx&7 so batch-b stencil is written
// from (and L2-resident on) the same XCD that gathers batch b.
__global__ __launch_bounds__(256)
void stencil_kernel(const float* __restrict__ data, uint4* __restrict__ st) {
    const int b   = blockIdx.x & 7;
    const int pix = (blockIdx.x >> 3) * 256 + threadIdx.x;
    const int oy = pix >> 6, ox = pix & 63;

    const float*  xbase = data + (size_t)b * CB * NPIX;
    const float2* gaff  = (const float2*)(xbase + (size_t)256 * NPIX);
    const float2* gtps  = (const float2*)(xbase + (size_t)384 * NPIX);
    uint4* stb = st + (size_t)b * NT4 * NPIX;

    const float fy  = ((float)oy / 63.0f) * 239.0f;
    const float fx  = ((float)ox / 63.0f) * 239.0f;
    const float fy0 = floorf(fy), fx0 = floorf(fx);
    const float wy1 = fy - fy0,  wx1 = fx - fx0;

#pragma unroll
    for (int t = 0; t < 4; ++t) {
        const int tty = t >> 1, ttx = t & 1;
        const float gyf = fy0 + (float)tty;
        const float gxf = fx0 + (float)ttx;
        float wt = (tty ? wy1 : 1.0f - wy1) * (ttx ? wx1 : 1.0f - wx1);
        if (gyf < 0.0f || gyf > 239.0f || gxf < 0.0f || gxf > 239.0f) wt = 0.0f;
        const int gyi = min(max((int)gyf, 0), GHH - 1);
        const int gxi = min(max((int)gxf, 0), GWW - 1);

        const float2 gt = gtps[gyi * GWW + gxi];
        const float sx  = (gt.x + 1.0f) * 0.5f * 239.0f;
        const float sy  = (gt.y + 1.0f) * 0.5f * 239.0f;
        const float sy0 = floorf(sy), sx0 = floorf(sx);
        const float wsy1 = sy - sy0,  wsx1 = sx - sx0;

#pragma unroll
        for (int s = 0; s < 4; ++s) {
            const int ssy = s >> 1, ssx = s & 1;
            const float ayf = sy0 + (float)ssy;
            const float axf = sx0 + (float)ssx;
            float ws = (ssy ? wsy1 : 1.0f - wsy1) * (ssx ? wsx1 : 1.0f - wsx1);
            if (ayf < 0.0f || ayf > 239.0f || axf < 0.0f || axf > 239.0f) ws = 0.0f;
            ws *= wt;
            const int ayi = min(max((int)ayf, 0), GHH - 1);
            const int axi = min(max((int)axf, 0), GWW - 1);

            const float2 ga = gaff[ayi * GWW + axi];
            const float qx  = (ga.x + 1.0f) * 0.5f * 63.0f;
            const float qy  = (ga.y + 1.0f) * 0.5f * 63.0f;
            const float qy0 = floorf(qy), qx0 = floorf(qx);
            const float wqy1 = qy - qy0,  wqx1 = qx - qx0;

            unsigned pk[4];
#pragma unroll
            for (int r = 0; r < 4; ++r) {
                const int rry = r >> 1, rrx = r & 1;
                const float byf = qy0 + (float)rry;
                const float bxf = qx0 + (float)rrx;
                float wr = (rry ? wqy1 : 1.0f - wqy1) * (rrx ? wqx1 : 1.0f - wqx1);
                if (byf < 0.0f || byf > 63.0f || bxf < 0.0f || bxf > 63.0f) wr = 0.0f;
                wr *= ws;
                const int byi = min(max((int)byf, 0), H - 1);
                const int bxi = min(max((int)bxf, 0), W - 1);
                pk[r] = pk_wi(wr, (unsigned)(byi * W + bxi));
            }
            stb[(size_t)(t * 4 + s) * NPIX + pix] = make_uint4(pk[0], pk[1], pk[2], pk[3]);
        }
    }
}

// ---------- kernel 2: gather over f16-packed LDS, v_fma_mix accumulate ----------
// grid: 8 b x 32 cg x 2 halves = 512 blocks x 1024 threads; 64 KB LDS each
// -> 2 blocks/CU, 32 waves/CU. Round-4 access pattern (1 px/thread per pg).
__global__ __launch_bounds__(1024, 8)
void gather_kernel(const float* __restrict__ data, const uint4* __restrict__ st,
                   float* __restrict__ out) {
    __shared__ uint4 xl[NPIX];   // 64 KB: pixel -> 8 channels packed f16
    const int tid  = threadIdx.x;
    const int b    = blockIdx.x & 7;        // XCD pinning heuristic
    const int cg   = (blockIdx.x >> 3) & 31;
    const int half = blockIdx.x >> 8;       // 0/1: pixel half
    const int c0   = cg * 8;

    const float* xbase = data + (size_t)b * CB * NPIX;
    const float* xc    = xbase + (size_t)c0 * NPIX;

    // stage full 8-channel image: 8 x float4 coalesced loads, register transpose,
    // pack to f16 via v_cvt_pkrtz (1 instr / 2 channels)
    {
        float4 va[8];
#pragma unroll
        for (int c = 0; c < 8; ++c)
            va[c] = ((const float4*)(xc + (size_t)c * NPIX))[tid];
#pragma unroll
        for (int k = 0; k < 4; ++k) {
            uint4 u;
            u.x = pk_f16(((const float*)&va[0])[k], ((const float*)&va[1])[k]);
            u.y = pk_f16(((const float*)&va[2])[k], ((const float*)&va[3])[k]);
            u.z = pk_f16(((const float*)&va[4])[k], ((const float*)&va[5])[k]);
            u.w = pk_f16(((const float*)&va[6])[k], ((const float*)&va[7])[k]);
            xl[tid * 4 + k] = u;
        }
    }
    __syncthreads();

    const uint4* stb = st + (size_t)b * NT4 * NPIX;

#pragma unroll
    for (int pg = 0; pg < 2; ++pg) {
        const int pix = half * 2048 + pg * 1024 + tid;
        float a0 = 0.f, a1 = 0.f, a2 = 0.f, a3 = 0.f;
        float a4 = 0.f, a5 = 0.f, a6 = 0.f, a7 = 0.f;

#pragma unroll 4
        for (int g = 0; g < NT4; ++g) {
            const uint4 s4 = stb[(size_t)g * NPIX + pix];
#pragma unroll
            for (int r = 0; r < 4; ++r) {
                const unsigned u = (&s4.x)[r];
                const float w = __uint_as_float(u & 0xffff0000u);
                const uint4 v = xl[u & 0xffffu];
                // fpext(f16) + fmaf -> v_fma_mix_f32 (op_sel selects hi/lo half)
                const __half2 h01 = *reinterpret_cast<const __half2*>(&v.x);
                const __half2 h23 = *reinterpret_cast<const __half2*>(&v.y);
                const __half2 h45 = *reinterpret_cast<const __half2*>(&v.z);
                const __half2 h67 = *reinterpret_cast<const __half2*>(&v.w);
                a0 = fmaf(w, __half2float(__low2half (h01)), a0);
                a1 = fmaf(w, __half2float(__high2half(h01)), a1);
                a2 = fmaf(w, __half2float(__low2half (h23)), a2);
                a3 = fmaf(w, __half2float(__high2half(h23)), a3);
                a4 = fmaf(w, __half2float(__low2half (h45)), a4);
                a5 = fmaf(w, __half2float(__high2half(h45)), a5);
                a6 = fmaf(w, __half2float(__low2half (h67)), a6);
                a7 = fmaf(w, __half2float(__high2half(h67)), a7);
            }
        }

        // residual (f32 from global, L2-resident) + coalesced plain stores
        float* o = out + ((size_t)b * CX + c0) * NPIX + pix;
        o[0 * NPIX] = xc[0 * NPIX + pix] + a0;
        o[1 * NPIX] = xc[1 * NPIX + pix] + a1;
        o[2 * NPIX] = xc[2 * NPIX + pix] + a2;
        o[3 * NPIX] = xc[3 * NPIX + pix] + a3;
        o[4 * NPIX] = xc[4 * NPIX + pix] + a4;
        o[5 * NPIX] = xc[5 * NPIX + pix] + a5;
        o[6 * NPIX] = xc[6 * NPIX + pix] + a6;
        o[7 * NPIX] = xc[7 * NPIX + pix] + a7;
    }
}

// ---------- fallback (round-2 proven kernel) if ws too small ----------
__global__ __launch_bounds__(1024, 4)
void warp_resblock_mono(const float* __restrict__ data, float* __restrict__ out) {
    const int tid = threadIdx.x;
    const int b   = blockIdx.x & 7;
    const int cg  = blockIdx.x >> 3;
    const int c0  = cg * 8;

    const float*  xbase = data + (size_t)b * CB * NPIX;
    const float2* gaff  = (const float2*)(xbase + (size_t)256 * NPIX);
    const float2* gtps  = (const float2*)(xbase + (size_t)384 * NPIX);

    __shared__ float4 xa[NPIX];
    __shared__ float4 xb[NPIX];
    {
        const float4* xs = (const float4*)(xbase + (size_t)c0 * NPIX);
        float4 va[4], vb[4];
#pragma unroll
        for (int cc = 0; cc < 4; ++cc) va[cc] = xs[(size_t)cc * 1024 + tid];
#pragma unroll
        for (int cc = 0; cc < 4; ++cc) vb[cc] = xs[(size_t)(4 + cc) * 1024 + tid];
#pragma unroll
        for (int k = 0; k < 4; ++k) {
            const int pix = tid * 4 + k;
            xa[pix] = make_float4(((const float*)&va[0])[k], ((const float*)&va[1])[k],
                                  ((const float*)&va[2])[k], ((const float*)&va[3])[k]);
            xb[pix] = make_float4(((const float*)&vb[0])[k], ((const float*)&vb[1])[k],
                                  ((const float*)&vb[2])[k], ((const float*)&vb[3])[k]);
        }
    }
    __syncthreads();

    for (int pg = 0; pg < 4; ++pg) {
        const int pix = pg * 1024 + tid;
        const int oy = pix >> 6, ox = pix & 63;
        float a0 = 0.f, a1 = 0.f, a2 = 0.f, a3 = 0.f;
        float a4 = 0.f, a5 = 0.f, a6 = 0.f, a7 = 0.f;

        const float fy  = ((float)oy / 63.0f) * 239.0f;
        const float fx  = ((float)ox / 63.0f) * 239.0f;
        const float fy0 = floorf(fy), fx0 = floorf(fx);
        const float wy1 = fy - fy0,  wx1 = fx - fx0;

#pragma unroll
        for (int t = 0; t < 4; ++t) {
            const int tty = t >> 1, ttx = t & 1;
            const float gyf = fy0 + (float)tty;
            const float gxf = fx0 + (float)ttx;
            float wt = (tty ? wy1 : 1.0f - wy1) * (ttx ? wx1 : 1.0f - wx1);
            if (gyf < 0.0f || gyf > 239.0f || gxf < 0.0f || gxf > 239.0f) wt = 0.0f;
            const int gyi = min(max((int)gyf, 0), GHH - 1);
            const int gxi = min(max((int)gxf, 0), GWW - 1);
            const float2 gt = gtps[gyi * GWW + gxi];
            const float sx  = (gt.x + 1.0f) * 0.5f * 239.0f;
            const float sy  = (gt.y + 1.0f) * 0.5f * 239.0f;
            const float sy0 = floorf(sy), sx0 = floorf(sx);
            const float wsy1 = sy - sy0,  wsx1 = sx - sx0;
#pragma unroll
            for (int s = 0; s < 4; ++s) {
                const int ssy = s >> 1, ssx = s & 1;
                const float ayf = sy0 + (float)ssy;
                const float axf = sx0 + (float)ssx;
                float ws = (ssy ? wsy1 : 1.0f - wsy1) * (ssx ? wsx1 : 1.0f - wsx1);
                if (ayf < 0.0f || ayf > 239.0f || axf < 0.0f || axf > 239.0f) ws = 0.0f;
                ws *= wt;
                const int ayi = min(max((int)ayf, 0), GHH - 1);
                const int axi = min(max((int)axf, 0), GWW - 1);
                const float2 ga = gaff[ayi * GWW + axi];
                const float qx  = (ga.x + 1.0f) * 0.5f * 63.0f;
                const float qy  = (ga.y + 1.0f) * 0.5f * 63.0f;
                const float qy0 = floorf(qy), qx0 = floorf(qx);
                const float wqy1 = qy - qy0,  wqx1 = qx - qx0;
#pragma unroll
                for (int r = 0; r < 4; ++r) {
                    const int rry = r >> 1, rrx = r & 1;
                    const float byf = qy0 + (float)rry;
                    const float bxf = qx0 + (float)rrx;
                    float wr = (rry ? wqy1 : 1.0f - wqy1) * (rrx ? wqx1 : 1.0f - wqx1);
                    if (byf < 0.0f || byf > 63.0f || bxf < 0.0f || bxf > 63.0f) wr = 0.0f;
                    wr *= ws;
                    const int byi = min(max((int)byf, 0), H - 1);
                    const int bxi = min(max((int)bxf, 0), W - 1);
                    const int idx = byi * W + bxi;
                    const float4 pa = xa[idx];
                    const float4 pb = xb[idx];
                    a0 = fmaf(wr, pa.x, a0); a1 = fmaf(wr, pa.y, a1);
                    a2 = fmaf(wr, pa.z, a2); a3 = fmaf(wr, pa.w, a3);
                    a4 = fmaf(wr, pb.x, a4); a5 = fmaf(wr, pb.y, a5);
                    a6 = fmaf(wr, pb.z, a6); a7 = fmaf(wr, pb.w, a7);
                }
            }
        }
        const float4 ra = xa[pix];
        const float4 rb = xb[pix];
        float* o = out + ((size_t)b * CX + c0) * NPIX + pix;
        o[0 * NPIX] = ra.x + a0; o[1 * NPIX] = ra.y + a1;
        o[2 * NPIX] = ra.z + a2; o[3 * NPIX] = ra.w + a3;
        o[4 * NPIX] = rb.x + a4; o[5 * NPIX] = rb.y + a5;
        o[6 * NPIX] = rb.z + a6; o[7 * NPIX] = rb.w + a7;
    }
}

extern "C" void kernel_launch(void* const* d_in, const int* in_sizes, int n_in,
                              void* d_out, int out_size, void* d_ws, size_t ws_size,
                              hipStream_t stream) {
    (void)in_sizes; (void)n_in; (void)out_size;
    const float* data = (const float*)d_in[0];
    float* out = (float*)d_out;
    const size_t ws_needed = (size_t)8 * NT4 * NPIX * sizeof(uint4);  // 8.39 MB

    if (ws_size >= ws_needed) {
        uint4* st = (uint4*)d_ws;
        hipLaunchKernelGGL(stencil_kernel, dim3(128), dim3(256), 0, stream, data, st);
        hipLaunchKernelGGL(gather_kernel, dim3(512), dim3(1024), 0, stream, data, st, out);
    } else {
        hipLaunchKernelGGL(warp_resblock_mono, dim3(256), dim3(1024), 0, stream, data, out);
    }
}

// Round 8
// 42.807 us; speedup vs baseline: 1.2894x; 1.2376x over previous
//
#include <hip/hip_runtime.h>
#include <hip/hip_fp16.h>

#define H 64
#define W 64
#define NPIX 4096          // 64*64
#define GHH 240
#define GWW 240
#define CB 512             // total channels in data
#define CX 256             // x channels
#define NT4  16            // taps packed 4-per-uint4

// ---------- helpers ----------
// pack: byte-offset (idx*16, <=65520) in HIGH 16, f16 weight in LOW 16.
// gather unpack: addr = u>>16 (one lshr); weight consumed as f16 lo-half by v_fma_mix.
static __device__ __forceinline__ unsigned pk_wi(float w, unsigned idx) {
    const unsigned short hw = __half_as_ushort(__float2half(w));
    return ((idx * 16u) << 16) | (unsigned)hw;
}
// pack two f32 -> packed f16 pair (v_cvt_pkrtz_f16_f32, one instruction)
static __device__ __forceinline__ unsigned pk_f16(float a, float b) {
    __half2 h = __floats2half2_rn(a, b);
    return *reinterpret_cast<unsigned*>(&h);
}

// ---------- kernel 1: per (b,pixel) 64-tap packed stencil -> ws ----------
// grid: 256 blocks x 128 threads (all CUs); b = blockIdx&7 -> XCD pinning so
// batch-b stencil lands in the L2 of the XCD that gathers batch b.
__global__ __launch_bounds__(128)
void stencil_kernel(const float* __restrict__ data, uint4* __restrict__ st) {
    const int b   = blockIdx.x & 7;
    const int pix = (blockIdx.x >> 3) * 128 + threadIdx.x;
    const int oy = pix >> 6, ox = pix & 63;

    const float*  xbase = data + (size_t)b * CB * NPIX;
    const float2* gaff  = (const float2*)(xbase + (size_t)256 * NPIX);
    const float2* gtps  = (const float2*)(xbase + (size_t)384 * NPIX);
    uint4* stb = st + (size_t)b * NT4 * NPIX;

    const float fy  = ((float)oy / 63.0f) * 239.0f;
    const float fx  = ((float)ox / 63.0f) * 239.0f;
    const float fy0 = floorf(fy), fx0 = floorf(fx);
    const float wy1 = fy - fy0,  wx1 = fx - fx0;

#pragma unroll
    for (int t = 0; t < 4; ++t) {
        const int tty = t >> 1, ttx = t & 1;
        const float gyf = fy0 + (float)tty;
        const float gxf = fx0 + (float)ttx;
        float wt = (tty ? wy1 : 1.0f - wy1) * (ttx ? wx1 : 1.0f - wx1);
        if (gyf < 0.0f || gyf > 239.0f || gxf < 0.0f || gxf > 239.0f) wt = 0.0f;
        const int gyi = min(max((int)gyf, 0), GHH - 1);
        const int gxi = min(max((int)gxf, 0), GWW - 1);

        const float2 gt = gtps[gyi * GWW + gxi];
        const float sx  = (gt.x + 1.0f) * 0.5f * 239.0f;
        const float sy  = (gt.y + 1.0f) * 0.5f * 239.0f;
        const float sy0 = floorf(sy), sx0 = floorf(sx);
        const float wsy1 = sy - sy0,  wsx1 = sx - sx0;

#pragma unroll
        for (int s = 0; s < 4; ++s) {
            const int ssy = s >> 1, ssx = s & 1;
            const float ayf = sy0 + (float)ssy;
            const float axf = sx0 + (float)ssx;
            float ws = (ssy ? wsy1 : 1.0f - wsy1) * (ssx ? wsx1 : 1.0f - wsx1);
            if (ayf < 0.0f || ayf > 239.0f || axf < 0.0f || axf > 239.0f) ws = 0.0f;
            ws *= wt;
            const int ayi = min(max((int)ayf, 0), GHH - 1);
            const int axi = min(max((int)axf, 0), GWW - 1);

            const float2 ga = gaff[ayi * GWW + axi];
            const float qx  = (ga.x + 1.0f) * 0.5f * 63.0f;
            const float qy  = (ga.y + 1.0f) * 0.5f * 63.0f;
            const float qy0 = floorf(qy), qx0 = floorf(qx);
            const float wqy1 = qy - qy0,  wqx1 = qx - qx0;

            unsigned pk[4];
#pragma unroll
            for (int r = 0; r < 4; ++r) {
                const int rry = r >> 1, rrx = r & 1;
                const float byf = qy0 + (float)rry;
                const float bxf = qx0 + (float)rrx;
                float wr = (rry ? wqy1 : 1.0f - wqy1) * (rrx ? wqx1 : 1.0f - wqx1);
                if (byf < 0.0f || byf > 63.0f || bxf < 0.0f || bxf > 63.0f) wr = 0.0f;
                wr *= ws;
                const int byi = min(max((int)byf, 0), H - 1);
                const int bxi = min(max((int)bxf, 0), W - 1);
                pk[r] = pk_wi(wr, (unsigned)(byi * W + bxi));
            }
            stb[(size_t)(t * 4 + s) * NPIX + pix] = make_uint4(pk[0], pk[1], pk[2], pk[3]);
        }
    }
}

// ---------- kernel 2: gather over f16-packed LDS, fma_mix accumulate ----------
// grid: 8 b x 32 cg x 2 halves = 512 blocks x 1024 threads; 64 KB LDS each
// -> 2 blocks/CU, 32 waves/CU. Depth-3 stencil-load pipeline, hoisted residuals.
__global__ __launch_bounds__(1024, 8)
void gather_kernel(const float* __restrict__ data, const uint4* __restrict__ st,
                   float* __restrict__ out) {
    __shared__ uint4 xl[NPIX];   // 64 KB: pixel -> 8 channels packed f16
    const int tid  = threadIdx.x;
    const int b    = blockIdx.x & 7;        // XCD pinning heuristic
    const int cg   = (blockIdx.x >> 3) & 31;
    const int half = blockIdx.x >> 8;       // 0/1: pixel half
    const int c0   = cg * 8;

    const float* xbase = data + (size_t)b * CB * NPIX;
    const float* xc    = xbase + (size_t)c0 * NPIX;

    // stage full 8-channel image: 8 x float4 coalesced loads, register transpose,
    // pack to f16 via v_cvt_pkrtz (1 instr / 2 channels)
    {
        float4 va[8];
#pragma unroll
        for (int c = 0; c < 8; ++c)
            va[c] = ((const float4*)(xc + (size_t)c * NPIX))[tid];
#pragma unroll
        for (int k = 0; k < 4; ++k) {
            uint4 u;
            u.x = pk_f16(((const float*)&va[0])[k], ((const float*)&va[1])[k]);
            u.y = pk_f16(((const float*)&va[2])[k], ((const float*)&va[3])[k]);
            u.z = pk_f16(((const float*)&va[4])[k], ((const float*)&va[5])[k]);
            u.w = pk_f16(((const float*)&va[6])[k], ((const float*)&va[7])[k]);
            xl[tid * 4 + k] = u;
        }
    }
    __syncthreads();

    const uint4* stb = st + (size_t)b * NT4 * NPIX;
    const char*  xlb = (const char*)xl;

    for (int pg = 0; pg < 2; ++pg) {
        const int pix = half * 2048 + pg * 1024 + tid;

        // hoisted residual loads: in flight across the whole gather loop
        float res[8];
#pragma unroll
        for (int c = 0; c < 8; ++c) res[c] = xc[(size_t)c * NPIX + pix];

        float a0 = 0.f, a1 = 0.f, a2 = 0.f, a3 = 0.f;
        float a4 = 0.f, a5 = 0.f, a6 = 0.f, a7 = 0.f;

        // depth-3 software pipeline on stencil loads
        uint4 s_c  = stb[(size_t)0 * NPIX + pix];
        uint4 s_n1 = stb[(size_t)1 * NPIX + pix];
        uint4 s_n2 = stb[(size_t)2 * NPIX + pix];

#pragma unroll
        for (int g = 0; g < NT4; ++g) {
            const uint4 s4 = s_c;
            s_c = s_n1; s_n1 = s_n2;
            if (g + 3 < NT4) s_n2 = stb[(size_t)(g + 3) * NPIX + pix];

#pragma unroll
            for (int r = 0; r < 4; ++r) {
                const unsigned u = (&s4.x)[r];
                // weight: f16 in low half -> fma_mix reads it directly
                const float w = __half2float(__ushort_as_half((unsigned short)(u & 0xffffu)));
                const uint4 v = *(const uint4*)(xlb + (u >> 16));   // byte offset pre-scaled
                const __half2 h01 = *reinterpret_cast<const __half2*>(&v.x);
                const __half2 h23 = *reinterpret_cast<const __half2*>(&v.y);
                const __half2 h45 = *reinterpret_cast<const __half2*>(&v.z);
                const __half2 h67 = *reinterpret_cast<const __half2*>(&v.w);
                a0 = fmaf(w, __half2float(__low2half (h01)), a0);
                a1 = fmaf(w, __half2float(__high2half(h01)), a1);
                a2 = fmaf(w, __half2float(__low2half (h23)), a2);
                a3 = fmaf(w, __half2float(__high2half(h23)), a3);
                a4 = fmaf(w, __half2float(__low2half (h45)), a4);
                a5 = fmaf(w, __half2float(__high2half(h45)), a5);
                a6 = fmaf(w, __half2float(__low2half (h67)), a6);
                a7 = fmaf(w, __half2float(__high2half(h67)), a7);
            }
        }

        // residual add + coalesced plain stores (L2 write-combined, full lines)
        float* o = out + ((size_t)b * CX + c0) * NPIX + pix;
        o[0 * NPIX] = res[0] + a0;
        o[1 * NPIX] = res[1] + a1;
        o[2 * NPIX] = res[2] + a2;
        o[3 * NPIX] = res[3] + a3;
        o[4 * NPIX] = res[4] + a4;
        o[5 * NPIX] = res[5] + a5;
        o[6 * NPIX] = res[6] + a6;
        o[7 * NPIX] = res[7] + a7;
    }
}

// ---------- fallback (round-2 proven kernel) if ws too small ----------
__global__ __launch_bounds__(1024, 4)
void warp_resblock_mono(const float* __restrict__ data, float* __restrict__ out) {
    const int tid = threadIdx.x;
    const int b   = blockIdx.x & 7;
    const int cg  = blockIdx.x >> 3;
    const int c0  = cg * 8;

    const float*  xbase = data + (size_t)b * CB * NPIX;
    const float2* gaff  = (const float2*)(xbase + (size_t)256 * NPIX);
    const float2* gtps  = (const float2*)(xbase + (size_t)384 * NPIX);

    __shared__ float4 xa[NPIX];
    __shared__ float4 xb[NPIX];
    {
        const float4* xs = (const float4*)(xbase + (size_t)c0 * NPIX);
        float4 va[4], vb[4];
#pragma unroll
        for (int cc = 0; cc < 4; ++cc) va[cc] = xs[(size_t)cc * 1024 + tid];
#pragma unroll
        for (int cc = 0; cc < 4; ++cc) vb[cc] = xs[(size_t)(4 + cc) * 1024 + tid];
#pragma unroll
        for (int k = 0; k < 4; ++k) {
            const int pix = tid * 4 + k;
            xa[pix] = make_float4(((const float*)&va[0])[k], ((const float*)&va[1])[k],
                                  ((const float*)&va[2])[k], ((const float*)&va[3])[k]);
            xb[pix] = make_float4(((const float*)&vb[0])[k], ((const float*)&vb[1])[k],
                                  ((const float*)&vb[2])[k], ((const float*)&vb[3])[k]);
        }
    }
    __syncthreads();

    for (int pg = 0; pg < 4; ++pg) {
        const int pix = pg * 1024 + tid;
        const int oy = pix >> 6, ox = pix & 63;
        float a0 = 0.f, a1 = 0.f, a2 = 0.f, a3 = 0.f;
        float a4 = 0.f, a5 = 0.f, a6 = 0.f, a7 = 0.f;

        const float fy  = ((float)oy / 63.0f) * 239.0f;
        const float fx  = ((float)ox / 63.0f) * 239.0f;
        const float fy0 = floorf(fy), fx0 = floorf(fx);
        const float wy1 = fy - fy0,  wx1 = fx - fx0;

#pragma unroll
        for (int t = 0; t < 4; ++t) {
            const int tty = t >> 1, ttx = t & 1;
            const float gyf = fy0 + (float)tty;
            const float gxf = fx0 + (float)ttx;
            float wt = (tty ? wy1 : 1.0f - wy1) * (ttx ? wx1 : 1.0f - wx1);
            if (gyf < 0.0f || gyf > 239.0f || gxf < 0.0f || gxf > 239.0f) wt = 0.0f;
            const int gyi = min(max((int)gyf, 0), GHH - 1);
            const int gxi = min(max((int)gxf, 0), GWW - 1);
            const float2 gt = gtps[gyi * GWW + gxi];
            const float sx  = (gt.x + 1.0f) * 0.5f * 239.0f;
            const float sy  = (gt.y + 1.0f) * 0.5f * 239.0f;
            const float sy0 = floorf(sy), sx0 = floorf(sx);
            const float wsy1 = sy - sy0,  wsx1 = sx - sx0;
#pragma unroll
            for (int s = 0; s < 4; ++s) {
                const int ssy = s >> 1, ssx = s & 1;
                const float ayf = sy0 + (float)ssy;
                const float axf = sx0 + (float)ssx;
                float ws = (ssy ? wsy1 : 1.0f - wsy1) * (ssx ? wsx1 : 1.0f - wsx1);
                if (ayf < 0.0f || ayf > 239.0f || axf < 0.0f || axf > 239.0f) ws = 0.0f;
                ws *= wt;
                const int ayi = min(max((int)ayf, 0), GHH - 1);
                const int axi = min(max((int)axf, 0), GWW - 1);
                const float2 ga = gaff[ayi * GWW + axi];
                const float qx  = (ga.x + 1.0f) * 0.5f * 63.0f;
                const float qy  = (ga.y + 1.0f) * 0.5f * 63.0f;
                const float qy0 = floorf(qy), qx0 = floorf(qx);
                const float wqy1 = qy - qy0,  wqx1 = qx - qx0;
#pragma unroll
                for (int r = 0; r < 4; ++r) {
                    const int rry = r >> 1, rrx = r & 1;
                    const float byf = qy0 + (float)rry;
                    const float bxf = qx0 + (float)rrx;
                    float wr = (rry ? wqy1 : 1.0f - wqy1) * (rrx ? wqx1 : 1.0f - wqx1);
                    if (byf < 0.0f || byf > 63.0f || bxf < 0.0f || bxf > 63.0f) wr = 0.0f;
                    wr *= ws;
                    const int byi = min(max((int)byf, 0), H - 1);
                    const int bxi = min(max((int)bxf, 0), W - 1);
                    const int idx = byi * W + bxi;
                    const float4 pa = xa[idx];
                    const float4 pb = xb[idx];
                    a0 = fmaf(wr, pa.x, a0); a1 = fmaf(wr, pa.y, a1);
                    a2 = fmaf(wr, pa.z, a2); a3 = fmaf(wr, pa.w, a3);
                    a4 = fmaf(wr, pb.x, a4); a5 = fmaf(wr, pb.y, a5);
                    a6 = fmaf(wr, pb.z, a6); a7 = fmaf(wr, pb.w, a7);
                }
            }
        }
        const float4 ra = xa[pix];
        const float4 rb = xb[pix];
        float* o = out + ((size_t)b * CX + c0) * NPIX + pix;
        o[0 * NPIX] = ra.x + a0; o[1 * NPIX] = ra.y + a1;
        o[2 * NPIX] = ra.z + a2; o[3 * NPIX] = ra.w + a3;
        o[4 * NPIX] = rb.x + a4; o[5 * NPIX] = rb.y + a5;
        o[6 * NPIX] = rb.z + a6; o[7 * NPIX] = rb.w + a7;
    }
}

extern "C" void kernel_launch(void* const* d_in, const int* in_sizes, int n_in,
                              void* d_out, int out_size, void* d_ws, size_t ws_size,
                              hipStream_t stream) {
    (void)in_sizes; (void)n_in; (void)out_size;
    const float* data = (const float*)d_in[0];
    float* out = (float*)d_out;
    const size_t ws_needed = (size_t)8 * NT4 * NPIX * sizeof(uint4);  // 8.39 MB

    if (ws_size >= ws_needed) {
        uint4* st = (uint4*)d_ws;
        hipLaunchKernelGGL(stencil_kernel, dim3(256), dim3(128), 0, stream, data, st);
        hipLaunchKernelGGL(gather_kernel, dim3(512), dim3(1024), 0, stream, data, st, out);
    } else {
        hipLaunchKernelGGL(warp_resblock_mono, dim3(256), dim3(1024), 0, stream, data, out);
    }
}